// Round 3
// baseline (292.964 us; speedup 1.0000x reference)
//
#include <hip/hip_runtime.h>
#include <math.h>

#define NB 16
#define NC 8
#define HH 512
#define WW 512
#define HW (HH * WW)
#define CHW (NC * HW)

__device__ __forceinline__ float sigf(float x) {
    return __fdividef(1.0f, 1.0f + __expf(-x));
}

// t is exactly 0.0 or 1.0: BCE elem = -max(log(t ? p : 1-p), -100)
__device__ __forceinline__ float bce_term(float t, float p) {
    float q = (t > 0.5f) ? p : (1.0f - p);
    return -fmaxf(__logf(q), -100.0f);
}

__device__ __forceinline__ void ld4(const float* p, float* o) {
    float4 v = *(const float4*)p;
    o[0] = v.x; o[1] = v.y; o[2] = v.z; o[3] = v.w;
}

// waves_per_eu(2,4): allow the allocator 128-256 VGPRs so all ~29 dwordx4
// loads stay in flight (at VGPR=64 the scheduler serialized them ~3 at a time
// -> latency-bound at 18% HBM BW, round-2 evidence).
__global__ __launch_bounds__(256)
__attribute__((amdgpu_waves_per_eu(2, 4)))
void bicon_loss_kernel(
    const float* __restrict__ c_map,
    const float* __restrict__ target,
    const float* __restrict__ con_target,
    float* __restrict__ out)
{
    const int tid = blockIdx.x * 256 + threadIdx.x;   // one thread = 4 pixels along w
    const int w0 = (tid & 127) << 2;                  // 128 groups of 4 per row
    const int h  = (tid >> 7) & (HH - 1);
    const int b  = tid >> 16;

    const float* cm = c_map      + b * CHW + h * WW + w0;
    const float* ct = con_target + b * CHW + h * WW + w0;

    const bool hu = (h > 0), hd = (h < HH - 1);       // wave-uniform
    const bool wl = (w0 > 0), wr = (w0 + 4 < WW);     // false only for 2 lanes per row
    const int ru = hu ? -WW : 0;                      // clamped row offsets (safe addresses)
    const int rd = hd ?  WW : 0;

    // ---- all global loads issued up front (23 x dwordx4 + 6 x dword) ----
    float cv[8][4];
    #pragma unroll
    for (int c = 0; c < 8; ++c) ld4(cm + c * HW, cv[c]);

    float u6r[4], u5r[4], u7r[4];                     // row h-1: c6(dw0), c5(dw+1), c7(dw-1)
    ld4(cm + 6 * HW + ru, u6r);
    ld4(cm + 5 * HW + ru, u5r);
    ld4(cm + 7 * HW + ru, u7r);

    float d1r[4], d2r[4], d0r[4];                     // row h+1: c1(dw0), c2(dw+1), c0(dw-1)
    ld4(cm + 1 * HW + rd, d1r);
    ld4(cm + 2 * HW + rd, d2r);
    ld4(cm + 0 * HW + rd, d0r);

    float tv[8][4];
    #pragma unroll
    for (int c = 0; c < 8; ++c) ld4(ct + c * HW, tv[c]);

    float tg[4];
    ld4(target + b * HW + h * WW + w0, tg);

    // edge scalars (2 active lanes per row get real neighbors; rest clamp)
    const float u5e = cm[5 * HW + ru + (wr ? 4 : 0)];
    const float u7e = cm[7 * HW + ru + (wl ? -1 : 0)];
    const float d2e = cm[2 * HW + rd + (wr ? 4 : 0)];
    const float d0e = cm[0 * HW + rd + (wl ? -1 : 0)];
    const float m4e = cm[4 * HW + (wl ? -1 : 0)];     // c4 @ w0-1
    const float m3e = cm[3 * HW + (wr ? 4 : 0)];      // c3 @ w0+4

    // ---- center sigmoids ----
    float sp[8][4];
    #pragma unroll
    for (int c = 0; c < 8; ++c)
        #pragma unroll
        for (int j = 0; j < 4; ++j) sp[c][j] = sigf(cv[c][j]);

    float acc_con = 0.0f, acc_bi = 0.0f, acc_de = 0.0f;
    #pragma unroll
    for (int j = 0; j < 4; ++j) {
        // neighbor p values (zero where the shift pads)
        const float n6 = hu ? sigf(u6r[j]) : 0.0f;
        const float n5 = (j < 3) ? (hu ? sigf(u5r[j + 1]) : 0.0f)
                                 : ((hu && wr) ? sigf(u5e) : 0.0f);
        const float n7 = (j > 0) ? (hu ? sigf(u7r[j - 1]) : 0.0f)
                                 : ((hu && wl) ? sigf(u7e) : 0.0f);
        const float dn1 = hd ? sigf(d1r[j]) : 0.0f;
        const float dn2 = (j < 3) ? (hd ? sigf(d2r[j + 1]) : 0.0f)
                                  : ((hd && wr) ? sigf(d2e) : 0.0f);
        const float dn0 = (j > 0) ? (hd ? sigf(d0r[j - 1]) : 0.0f)
                                  : ((hd && wl) ? sigf(d0e) : 0.0f);
        const float m4 = (j > 0) ? sp[4][j - 1] : (wl ? sigf(m4e) : 0.0f);
        const float m3 = (j < 3) ? sp[3][j + 1] : (wr ? sigf(m3e) : 0.0f);

        const float a1 = sp[3][j] * m4;    // c3 * shift_right(c4)
        const float a2 = sp[4][j] * m3;    // c4 * shift_left(c3)
        const float a3 = sp[1][j] * n6;    // c1 * shift_down(c6)
        const float a4 = sp[6][j] * dn1;   // c6 * shift_up(c1)
        const float a5 = sp[2][j] * n5;    // c2 * l-b(c5)
        const float a6 = sp[5][j] * dn2;   // c5 * r-a(c2)
        const float a7 = sp[0][j] * n7;    // c0 * r-b(c7)
        const float a8 = sp[7][j] * dn0;   // c7 * l-a(c0)

        const float vote[8] = { a7, a3, a5, a1, a2, a6, a4, a8 };

        float sum_conn = 0.0f;
        #pragma unroll
        for (int c = 0; c < 8; ++c) sum_conn += tv[c][j];

        #pragma unroll
        for (int c = 0; c < 8; ++c) {
            acc_con += bce_term(tv[c][j], sp[c][j]);
            acc_bi  += bce_term(tv[c][j], vote[c]);
        }

        const float glo = (a1 + a2 + a3 + a4 + a5 + a6 + a7 + a8) * 0.125f;
        float mn = vote[0];
        #pragma unroll
        for (int c = 1; c < 8; ++c) mn = fminf(mn, vote[c]);

        const bool edge = (sum_conn < 8.0f) && (sum_conn > 0.0f);
        const float dec = edge ? (1.0f - mn) : glo;
        acc_de += bce_term(tg[j], dec);
    }

    float local = fmaf(0.8f, acc_con, fmaf(0.2f, acc_bi, acc_de));

    // ---- reduction: wave64 shuffle -> LDS -> one atomic per block ----
    #pragma unroll
    for (int off = 32; off > 0; off >>= 1)
        local += __shfl_down(local, off, 64);

    __shared__ float wsum[4];
    const int lane = threadIdx.x & 63;
    const int wid  = threadIdx.x >> 6;
    if (lane == 0) wsum[wid] = local;
    __syncthreads();
    if (threadIdx.x == 0) {
        atomicAdd(out, wsum[0] + wsum[1] + wsum[2] + wsum[3]);
    }
}

extern "C" void kernel_launch(void* const* d_in, const int* in_sizes, int n_in,
                              void* d_out, int out_size, void* d_ws, size_t ws_size,
                              hipStream_t stream) {
    const float* c_map      = (const float*)d_in[0];
    const float* target     = (const float*)d_in[1];
    const float* con_target = (const float*)d_in[2];
    float* out = (float*)d_out;

    hipMemsetAsync(out, 0, sizeof(float), stream);

    const int total_threads = NB * HH * (WW / 4);   // 1,048,576
    const int blocks = total_threads / 256;         // 4096
    bicon_loss_kernel<<<blocks, 256, 0, stream>>>(c_map, target, con_target, out);
}

// Round 4
// 291.707 us; speedup vs baseline: 1.0043x; 1.0043x over previous
//
#include <hip/hip_runtime.h>
#include <math.h>

#define NB 16
#define NC 8
#define HH 512
#define WW 512
#define HW (HH * WW)
#define CHW (NC * HW)

typedef const __attribute__((address_space(1))) void* gvp;
typedef __attribute__((address_space(3))) void*       lvp;

__device__ __forceinline__ float sigf(float x) {
    return __fdividef(1.0f, 1.0f + __expf(-x));
}

// t is exactly 0.0 or 1.0: BCE elem = -max(log(t ? p : 1-p), -100)
__device__ __forceinline__ float bce_term(float t, float p) {
    float q = (t > 0.5f) ? p : (1.0f - p);
    return -fmaxf(__logf(q), -100.0f);
}

__device__ __forceinline__ void ld4(const float* p, float* o) {
    float4 v = *(const float4*)p;
    o[0] = v.x; o[1] = v.y; o[2] = v.z; o[3] = v.w;
}

// Block = 256 threads, tile = full image width (512 px) x 2 rows.
// c_map is staged through LDS with global_load_lds (no VGPR destinations ->
// all staging loads in flight at once; one vmcnt drain at the barrier).
// R2/R3 evidence: VGPR-destination loads serialize with ~full latency each.
__global__ __launch_bounds__(256) void bicon_loss_kernel(
    const float* __restrict__ c_map,
    const float* __restrict__ target,
    const float* __restrict__ con_target,
    float* __restrict__ out)
{
    // 22 planes x 512 floats = 44 KB:
    //  planes 0..2   : row h0-1, channels 5,6,7
    //  planes 3..10  : row h0  , channels 0..7
    //  planes 11..18 : row h0+1, channels 0..7
    //  planes 19..21 : row h0+2, channels 0,1,2
    __shared__ float lds[22][WW];

    const int b    = blockIdx.x >> 8;          // 256 tiles per batch image
    const int h0   = (blockIdx.x & 255) << 1;  // 2 rows per tile
    const int tid  = threadIdx.x;
    const int wave = tid >> 6;
    const int lane = tid & 63;

    // ---- async DMA staging: 44 segments of 1 KB, 11 per wave ----
    for (int s = wave; s < 44; s += 4) {
        const int plane = s >> 1, half = s & 1;
        int ch, rel;
        if      (plane < 3)  { ch = 5 + plane;  rel = -1; }
        else if (plane < 11) { ch = plane - 3;  rel = 0;  }
        else if (plane < 19) { ch = plane - 11; rel = 1;  }
        else                 { ch = plane - 19; rel = 2;  }
        int rr = h0 + rel;
        rr = rr < 0 ? 0 : (rr > HH - 1 ? HH - 1 : rr);   // clamp; compute side selects 0
        const float* gp = c_map + b * CHW + ch * HW + rr * WW + half * 256 + lane * 4;
        __builtin_amdgcn_global_load_lds((gvp)gp, (lvp)&lds[plane][half * 256], 16, 0, 0);
    }

    const int r   = tid >> 7;            // tile row 0/1
    const int px0 = (tid & 127) << 2;    // 0..508
    const int gr  = h0 + r;

    // ---- direct global loads (single-use data): con_target 8x, target 1x ----
    const float* ct = con_target + b * CHW + gr * WW + px0;
    float tv[8][4];
    #pragma unroll
    for (int c = 0; c < 8; ++c) ld4(ct + c * HW, tv[c]);
    float tg[4];
    ld4(target + b * HW + gr * WW + px0, tg);

    __syncthreads();   // drains global_load_lds DMA + barrier

    const bool hu = gr > 0, hd = gr < HH - 1;
    const bool wl = px0 > 0, wr = px0 < WW - 4;

    const int cb = r ? 11 : 3;                       // center plane base
    const int pu5 = r ? 8 : 0, pu6 = r ? 9 : 1, pu7 = r ? 10 : 2;   // row gr-1
    const int pd0 = r ? 19 : 11, pd1 = r ? 20 : 12, pd2 = r ? 21 : 13; // row gr+1

    float sp[8][4];
    #pragma unroll
    for (int c = 0; c < 8; ++c) {
        float cv[4]; ld4(&lds[cb + c][px0], cv);
        #pragma unroll
        for (int j = 0; j < 4; ++j) sp[c][j] = sigf(cv[j]);
    }

    float u5[4], u6[4], u7[4], dd0[4], dd1[4], dd2[4];
    ld4(&lds[pu5][px0], u5);
    ld4(&lds[pu6][px0], u6);
    ld4(&lds[pu7][px0], u7);
    ld4(&lds[pd0][px0], dd0);
    ld4(&lds[pd1][px0], dd1);
    ld4(&lds[pd2][px0], dd2);
    const float e5  = lds[pu5][wr ? px0 + 4 : px0];
    const float e7  = lds[pu7][wl ? px0 - 1 : px0];
    const float e2  = lds[pd2][wr ? px0 + 4 : px0];
    const float e0  = lds[pd0][wl ? px0 - 1 : px0];
    const float m4e = lds[cb + 4][wl ? px0 - 1 : px0];
    const float m3e = lds[cb + 3][wr ? px0 + 4 : px0];

    float acc_con = 0.0f, acc_bi = 0.0f, acc_de = 0.0f;
    #pragma unroll
    for (int j = 0; j < 4; ++j) {
        const float n6  = hu ? sigf(u6[j]) : 0.0f;
        const float n5  = (j < 3) ? (hu ? sigf(u5[j + 1]) : 0.0f)
                                  : ((hu && wr) ? sigf(e5) : 0.0f);
        const float n7  = (j > 0) ? (hu ? sigf(u7[j - 1]) : 0.0f)
                                  : ((hu && wl) ? sigf(e7) : 0.0f);
        const float dn1 = hd ? sigf(dd1[j]) : 0.0f;
        const float dn2 = (j < 3) ? (hd ? sigf(dd2[j + 1]) : 0.0f)
                                  : ((hd && wr) ? sigf(e2) : 0.0f);
        const float dn0 = (j > 0) ? (hd ? sigf(dd0[j - 1]) : 0.0f)
                                  : ((hd && wl) ? sigf(e0) : 0.0f);
        const float m4  = (j > 0) ? sp[4][j - 1] : (wl ? sigf(m4e) : 0.0f);
        const float m3  = (j < 3) ? sp[3][j + 1] : (wr ? sigf(m3e) : 0.0f);

        const float a1 = sp[3][j] * m4;    // c3 * shift_right(c4)
        const float a2 = sp[4][j] * m3;    // c4 * shift_left(c3)
        const float a3 = sp[1][j] * n6;    // c1 * shift_down(c6)
        const float a4 = sp[6][j] * dn1;   // c6 * shift_up(c1)
        const float a5 = sp[2][j] * n5;    // c2 * left-bottom(c5)
        const float a6 = sp[5][j] * dn2;   // c5 * right-above(c2)
        const float a7 = sp[0][j] * n7;    // c0 * right-bottom(c7)
        const float a8 = sp[7][j] * dn0;   // c7 * left-above(c0)

        const float vote[8] = { a7, a3, a5, a1, a2, a6, a4, a8 };

        float sum_conn = 0.0f;
        #pragma unroll
        for (int c = 0; c < 8; ++c) sum_conn += tv[c][j];

        #pragma unroll
        for (int c = 0; c < 8; ++c) {
            acc_con += bce_term(tv[c][j], sp[c][j]);
            acc_bi  += bce_term(tv[c][j], vote[c]);
        }

        const float glo = (a1 + a2 + a3 + a4 + a5 + a6 + a7 + a8) * 0.125f;
        float mn = vote[0];
        #pragma unroll
        for (int c = 1; c < 8; ++c) mn = fminf(mn, vote[c]);

        const bool edge = (sum_conn < 8.0f) && (sum_conn > 0.0f);
        const float dec = edge ? (1.0f - mn) : glo;
        acc_de += bce_term(tg[j], dec);
    }

    float local = fmaf(0.8f, acc_con, fmaf(0.2f, acc_bi, acc_de));

    // ---- reduction: wave64 shuffle -> LDS -> one atomic per block ----
    #pragma unroll
    for (int off = 32; off > 0; off >>= 1)
        local += __shfl_down(local, off, 64);

    __shared__ float wsum[4];
    if (lane == 0) wsum[wave] = local;
    __syncthreads();
    if (tid == 0) {
        atomicAdd(out, wsum[0] + wsum[1] + wsum[2] + wsum[3]);
    }
}

extern "C" void kernel_launch(void* const* d_in, const int* in_sizes, int n_in,
                              void* d_out, int out_size, void* d_ws, size_t ws_size,
                              hipStream_t stream) {
    const float* c_map      = (const float*)d_in[0];
    const float* target     = (const float*)d_in[1];
    const float* con_target = (const float*)d_in[2];
    float* out = (float*)d_out;

    hipMemsetAsync(out, 0, sizeof(float), stream);

    const int blocks = NB * (HH / 2);    // 16 images x 256 row-pair tiles = 4096
    bicon_loss_kernel<<<blocks, 256, 0, stream>>>(c_map, target, con_target, out);
}